// Round 5
// baseline (5073.847 us; speedup 1.0000x reference)
//
#include <hip/hip_runtime.h>
#include <stdint.h>

// ---------------------------------------------------------------------------
// BiaffineNER: 2-layer biLSTM (coupled gates) + highway + biaffine span scores
// B=16 T=256 D=768 H=400 F=150 C=8.
//
// Round 4 (resubmit; prior attempt hit GPU-acquisition timeout, never ran):
// flag-free LSTM sync — sentinel data-polling.
//  * Per-timestep h buffers (T per dir per layer, +1 shared init buffer),
//    pre-set to 0xFF. 0xFFFFFFFF is unreachable for packed h (hi would be
//    a NaN bf16; |h|<1), so consumers poll the data itself: the load+MFMA
//    pass validates every word and redoes itself until all valid.
//  * Producer h-stores issue before output exports; exports sit after
//    barrier2 so their completion overlaps the next step's retry loop.
//  * No flags, no dedicated poll loop, no sampling latency.
// ---------------------------------------------------------------------------

#define B_  16
#define T_  256
#define D_  768
#define H_  400
#define HP  416      // K-padded H (13 tiles of 32)
#define G3  1200     // 3H
#define H2  800      // 2H
#define NS  20       // weight slices per direction
#define HS  20       // hidden units per slice
#define BT  4096     // B*T
#define HFRAG 6656   // u32s per h buffer: 13 kt * 512
#define SENT 0xFFFFFFFFu

using bf16x8 = __attribute__((ext_vector_type(8))) short;
using f32x4  = __attribute__((ext_vector_type(4))) float;
typedef unsigned short u16;
typedef unsigned int   u32;
typedef unsigned long long u64;

__device__ __forceinline__ u16 bf16_rne(float v){
  u32 u = __builtin_bit_cast(u32, v);
  u32 r = u + 0x7fffu + ((u >> 16) & 1u);
  return (u16)(r >> 16);
}
__device__ __forceinline__ void splitf(float v, u16 &hi, u16 &lo){
  u16 h = bf16_rne(v);
  float hf = __builtin_bit_cast(float, (u32)h << 16);
  hi = h;
  lo = bf16_rne(v - hf);
}

// --------------------------- elementwise fp32 -> bf16 hi/lo -----------------
__global__ void k_cvt(const float* __restrict__ in, u16* __restrict__ ohi,
                      u16* __restrict__ olo, long rows, int ld, int cr, int cp){
  long total = rows * (long)cp;
  for (long i = (long)blockIdx.x*blockDim.x + threadIdx.x; i < total;
       i += (long)gridDim.x*blockDim.x){
    long rr = i / cp; int j = (int)(i - rr*cp);
    float v = (j < cr) ? in[rr*(long)ld + j] : 0.f;
    u16 h,l; splitf(v,h,l);
    ohi[i] = h; olo[i] = l;
  }
}

// --------------------------- transpose + convert ----------------------------
struct TJob { const float* in; int ld, r0, R, Rpad, Cc; u16* ohi; u16* olo; };
struct TJobs { TJob j[12]; };
__global__ void k_tcvt(TJobs js){
  TJob jb = js.j[blockIdx.y];
  long total = (long)jb.Cc * jb.Rpad;
  for (long i = (long)blockIdx.x*blockDim.x + threadIdx.x; i < total;
       i += (long)gridDim.x*blockDim.x){
    long c = i / jb.Rpad; int rr = (int)(i - c*jb.Rpad);
    float v = (rr < jb.R) ? jb.in[(long)(jb.r0+rr)*jb.ld + c] : 0.f;
    u16 h,l; splitf(v,h,l);
    jb.ohi[i] = h; jb.olo[i] = l;
  }
}

// --------------------------- generic MFMA GEMM ------------------------------
// C[M x N] = A[M x Ka] * B^T[N x Ka]  (split-bf16 hi/lo, 3-term).
// MODE 0: out fp32 [M][Nstore] = acc + bias
// MODE 1: out = sigmoid(acc + bias)
// MODE 2: s1/e1 build -> bf16 hi/lo [M][160]: col<150 acc+bias; 150: 1.0; else 0
// MODE 3: biaffine stage1 -> bf16 hi/lo: col n -> (c=n/151, j=n%151) at
//         [(row*8+c)*160 + j]
// MODE 4: biaffine stage2 (per-z batch): A+=z*2048*Ka, B+=z*256*Ka,
//         out[((z*256 + row/8)*256 + col)*8 + (row&7)] = acc
template<int MODE>
__global__ __launch_bounds__(256)
void k_gemm(const u16* __restrict__ Ahi, const u16* __restrict__ Alo, int Ka,
            const u16* __restrict__ Bhi, const u16* __restrict__ Blo,
            const float* __restrict__ bias, float* __restrict__ out,
            u16* __restrict__ ohi, u16* __restrict__ olo,
            int Nreal, int Nstore)
{
  const int lane = threadIdx.x & 63, wave = threadIdx.x >> 6;
  long za = 0, zb = 0;
  if (MODE == 4){ za = (long)blockIdx.z*2048*Ka; zb = (long)blockIdx.z*256*Ka; }
  const u16* Ah = Ahi + za; const u16* Al = Alo + za;
  const u16* Bh = Bhi + zb; const u16* Bl = Blo + zb;

  const int row0 = blockIdx.y*64 + wave*16;
  const int col0 = blockIdx.x*64;
  const int r    = row0 + (lane & 15);
  const int kofs = (lane >> 4) * 8;

  const f32x4 vz = {0.f,0.f,0.f,0.f};
  f32x4 acc_hh[4], acc_x[4];
  #pragma unroll
  for (int nt=0; nt<4; ++nt){ acc_hh[nt]=vz; acc_x[nt]=vz; }
  const bf16x8 bz = {0,0,0,0,0,0,0,0};

  const int ktn = Ka >> 5;
  for (int kt=0; kt<ktn; ++kt){
    const int k0 = kt*32 + kofs;
    bf16x8 ah = *(const bf16x8*)(Ah + (long)r*Ka + k0);
    bf16x8 al = *(const bf16x8*)(Al + (long)r*Ka + k0);
    #pragma unroll
    for (int nt=0; nt<4; ++nt){
      int cc = col0 + nt*16 + (lane & 15);
      bf16x8 bh = bz, bl = bz;
      if (cc < Nreal){
        bh = *(const bf16x8*)(Bh + (long)cc*Ka + k0);
        bl = *(const bf16x8*)(Bl + (long)cc*Ka + k0);
      }
      acc_x[nt]  = __builtin_amdgcn_mfma_f32_16x16x32_bf16(al, bh, acc_x[nt], 0,0,0);
      acc_x[nt]  = __builtin_amdgcn_mfma_f32_16x16x32_bf16(ah, bl, acc_x[nt], 0,0,0);
      acc_hh[nt] = __builtin_amdgcn_mfma_f32_16x16x32_bf16(ah, bh, acc_hh[nt], 0,0,0);
    }
  }

  #pragma unroll
  for (int nt=0; nt<4; ++nt){
    int ocol = col0 + nt*16 + (lane & 15);
    if (ocol >= Nstore) continue;
    #pragma unroll
    for (int i=0; i<4; ++i){
      int orow = row0 + (lane>>4)*4 + i;
      float v = acc_hh[nt][i] + acc_x[nt][i];
      if (MODE == 0){
        out[(long)orow*Nstore + ocol] = v + bias[ocol];
      } else if (MODE == 1){
        float t = v + bias[ocol];
        out[(long)orow*Nstore + ocol] = 1.f/(1.f + expf(-t));
      } else if (MODE == 2){
        float t;
        if (ocol < 150) t = v + bias[ocol];
        else            t = (ocol == 150) ? 1.f : 0.f;
        u16 h,l; splitf(t,h,l);
        long idx = (long)orow*160 + ocol;
        ohi[idx] = h; olo[idx] = l;
      } else if (MODE == 3){
        int c = ocol/151, j = ocol - c*151;
        u16 h,l; splitf(v,h,l);
        long idx = ((long)orow*8 + c)*160 + j;
        ohi[idx] = h; olo[idx] = l;
      } else { // MODE 4
        int xx = orow >> 3, c = orow & 7;
        out[((((long)blockIdx.z*256) + xx)*256 + ocol)*8 + c] = v;
      }
    }
  }
}

// --------------------------- h-state init (fragment order) ------------------
// One HFRAG-word buffer holding h0 in fragment order (pads = 0, valid).
// u32 slot for (row,k): kt*512 + p*128 + l*2 + odd, l = sub*16 + row,
// with kt=k>>5, k'=k&31, sub=k'>>3, e=k'&7, p=e>>1, odd=e&1.
__global__ void k_init_hex(const float* __restrict__ h0, u32* __restrict__ out){
  for (int j = blockIdx.x*blockDim.x + threadIdx.x; j < HFRAG;
       j += gridDim.x*blockDim.x){
    int kt = j >> 9, rr = j & 511;
    int p = rr >> 7, rem = rr & 127, l = rem >> 1, odd = rem & 1;
    int sub = l >> 4;
    int k = kt*32 + sub*8 + p*2 + odd;
    u32 v = 0;
    if (k < H_){ u16 h,lo; splitf(h0[k],h,lo); v = ((u32)h<<16)|lo; }
    out[j] = v;
  }
}

// --------------------------- LSTM scan kernel -------------------------------
// grid = (NS, 2 dirs), 256 threads (4 waves, 1 wave/SIMD).
// hbuf: [2 dir][T][HFRAG] u32, pre-set to 0xFF (sentinel). init_hex: [HFRAG].
__global__ __launch_bounds__(256, 1)
void k_lstm(const float* __restrict__ Zx,                // [2][BT][G3]
            const u16* __restrict__ Wrhi, const u16* __restrict__ Wrlo, // [2][G3][HP]
            const float* __restrict__ c0,
            const u32* __restrict__ init_hex,
            u32* hbuf,
            float* __restrict__ outf,                    // [BT][H2]
            u16* __restrict__ out_hi, u16* __restrict__ out_lo)
{
  const int s = blockIdx.x, dir = blockIdx.y;
  const int tid = threadIdx.x, lane = tid & 63, wave = tid >> 6;
  const int u0 = s*HS;
  const int kofs = (lane >> 4) * 8;
  const bf16x8 bz = {0,0,0,0,0,0,0,0};
  const f32x4 vz = {0.f,0.f,0.f,0.f};

  // ---- persistent W fragments (B operand), cols = slice's 60 gate columns --
  const int lc = wave*16 + (lane & 15);          // local col 0..63 (>=60 pad)
  const bool colok = lc < 3*HS;
  int gcol = 0;
  if (colok){ int gg = lc/HS, idx = lc - gg*HS; gcol = gg*400 + u0 + idx; }
  const u16* wph = Wrhi + ((long)dir*G3 + gcol)*HP;
  const u16* wpl = Wrlo + ((long)dir*G3 + gcol)*HP;
  bf16x8 bh[13], bl[13];
  #pragma unroll
  for (int kt=0; kt<13; ++kt){
    bh[kt] = colok ? *(const bf16x8*)(wph + kt*32 + kofs) : bz;
    bl[kt] = colok ? *(const bf16x8*)(wpl + kt*32 + kofs) : bz;
  }

  // ---- update mapping: tid<160: b = tid/10, units ku=u0+2*(tid%10), ku+1 ----
  const bool upd = (tid < 160);
  const int b_a = tid/10, up_a = tid - (tid/10)*10;
  const int ku  = u0 + 2*up_a;                   // even unit index (global k)
  float c_a0 = 0.f, c_a1 = 0.f;
  if (upd){ c_a0 = c0[ku]; c_a1 = c0[ku+1]; }

  const float* zxd = Zx + (long)dir*BT*G3;
  const long zbase = (long)b_a*T_*G3 + ku;

  u32* hb_dir = hbuf + (long)dir*T_*HFRAG;
  // producer u32 slots for (b_a, ku, ku+1):
  const int pkt = ku >> 5, pk = ku & 31;
  const int psub = pk >> 3, pp = (pk & 7) >> 1;
  const int pslot = pkt*256 + pp*64 + (psub*16 + b_a);   // u64-pair index

  __shared__ float zlds[16][64];

  for (int q=0; q<T_; ++q){
    const int t = dir ? (T_-1-q) : q;

    // prefetch Zx (overlaps the data-poll below)
    float2 zxi = {0.f,0.f}, zxj = {0.f,0.f}, zxo = {0.f,0.f};
    if (upd){
      const float* zp = zxd + zbase + (long)t*G3;
      zxi = *(const float2*)(zp);
      zxj = *(const float2*)(zp + 400);
      zxo = *(const float2*)(zp + 800);
    }

    // ---- sentinel-polling load+MFMA pass: redo until every word valid ----
    const u64* hq = (const u64*)((q == 0) ? init_hex
                                          : hb_dir + (long)(q-1)*HFRAG);
    f32x4 a0, a1, a2;
    while (true){
      a0 = vz; a1 = vz; a2 = vz;
      bool ok = true;
      #pragma unroll
      for (int kt=0; kt<13; ++kt){
        bf16x8 ah, al;
        #pragma unroll
        for (int p=0; p<4; ++p){
          u64 d = 0;
          const bool pad = (kt == 12) && (lane >= 32);   // never produced
          if (!pad){
            d = __hip_atomic_load(hq + kt*256 + p*64 + lane, __ATOMIC_RELAXED,
                                  __HIP_MEMORY_SCOPE_AGENT);
            ok = ok & ((u32)d != SENT) & ((u32)(d >> 32) != SENT);
          }
          u32 w0 = (u32)d, w1 = (u32)(d >> 32);
          ah[2*p]   = (short)(w0 >> 16); al[2*p]   = (short)(w0 & 0xffffu);
          ah[2*p+1] = (short)(w1 >> 16); al[2*p+1] = (short)(w1 & 0xffffu);
        }
        a0 = __builtin_amdgcn_mfma_f32_16x16x32_bf16(al, bh[kt], a0, 0,0,0);
        a1 = __builtin_amdgcn_mfma_f32_16x16x32_bf16(ah, bl[kt], a1, 0,0,0);
        a2 = __builtin_amdgcn_mfma_f32_16x16x32_bf16(ah, bh[kt], a2, 0,0,0);
      }
      if (__all(ok)) break;
    }

    #pragma unroll
    for (int i=0; i<4; ++i)
      zlds[(lane>>4)*4 + i][lc] = a0[i] + a1[i] + a2[i];
    __syncthreads();                                   // barrier 1

    // read z from LDS, then release LDS for next step ASAP
    float vi0=0,vj0=0,vo0=0,vi1=0,vj1=0,vo1=0;
    if (upd){
      const int uu = 2*up_a;
      vi0 = zlds[b_a][uu]          + zxi.x;
      vj0 = zlds[b_a][HS + uu]     + zxj.x;
      vo0 = zlds[b_a][2*HS + uu]   + zxo.x;
      vi1 = zlds[b_a][uu+1]        + zxi.y;
      vj1 = zlds[b_a][HS + uu+1]   + zxj.y;
      vo1 = zlds[b_a][2*HS + uu+1] + zxo.y;
    }
    __syncthreads();                                   // barrier 2

    // gate math + h publish (stores complete while others poll)
    if (upd){
      float ig0 = 1.f/(1.f + expf(-vi0));
      c_a0 = (1.f - ig0)*c_a0 + ig0*tanhf(vj0);
      float hh0 = tanhf(c_a0) * (1.f/(1.f + expf(-vo0)));
      float ig1 = 1.f/(1.f + expf(-vi1));
      c_a1 = (1.f - ig1)*c_a1 + ig1*tanhf(vj1);
      float hh1 = tanhf(c_a1) * (1.f/(1.f + expf(-vo1)));
      u16 h0h,h0l,h1h,h1l;
      splitf(hh0,h0h,h0l); splitf(hh1,h1h,h1l);
      u32* dstb = hb_dir + (long)q*HFRAG;
      __hip_atomic_store(dstb + 2*pslot,     (((u32)h0h)<<16)|h0l,
                         __ATOMIC_RELAXED, __HIP_MEMORY_SCOPE_AGENT);
      __hip_atomic_store(dstb + 2*pslot + 1, (((u32)h1h)<<16)|h1l,
                         __ATOMIC_RELAXED, __HIP_MEMORY_SCOPE_AGENT);
      // exports (not on the recurrence critical path)
      long o = ((long)b_a*T_ + t)*H2 + dir*H_ + ku;
      float2 of = {hh0, hh1};
      *(float2*)(outf + o) = of;
      *(u32*)(out_hi + o) = (((u32)h1h)<<16) | h0h;
      *(u32*)(out_lo + o) = (((u32)h1l)<<16) | h0l;
    }
  }
}

// --------------------------- highway combine --------------------------------
__global__ void k_highway(const float* __restrict__ G, const float* __restrict__ o1,
                          const float* __restrict__ o0,
                          u16* __restrict__ chi, u16* __restrict__ clo, long n){
  for (long i = (long)blockIdx.x*blockDim.x + threadIdx.x; i < n;
       i += (long)gridDim.x*blockDim.x){
    float g = G[i];
    float v = g*o1[i] + (1.f - g)*o0[i];
    u16 h,l; splitf(v,h,l);
    chi[i] = h; clo[i] = l;
  }
}

// ---------------------------------------------------------------------------
extern "C" void kernel_launch(void* const* d_in, const int* in_sizes, int n_in,
                              void* d_out, int out_size, void* d_ws, size_t ws_size,
                              hipStream_t stream)
{
  (void)in_sizes; (void)n_in; (void)out_size; (void)ws_size;
  const float* x    = (const float*)d_in[0];
  const float* W_f0 = (const float*)d_in[1];
  const float* b_f0 = (const float*)d_in[2];
  const float* W_b0 = (const float*)d_in[3];
  const float* b_b0 = (const float*)d_in[4];
  const float* W_f1 = (const float*)d_in[5];
  const float* b_f1 = (const float*)d_in[6];
  const float* W_b1 = (const float*)d_in[7];
  const float* b_b1 = (const float*)d_in[8];
  const float* h0   = (const float*)d_in[9];
  const float* c0   = (const float*)d_in[10];
  const float* W_hw = (const float*)d_in[11];
  const float* b_hw = (const float*)d_in[12];
  const float* W_s  = (const float*)d_in[13];
  const float* b_s  = (const float*)d_in[14];
  const float* W_e  = (const float*)d_in[15];
  const float* b_e  = (const float*)d_in[16];
  const float* U    = (const float*)d_in[17];

  char* ws = (char*)d_ws;
  size_t off = 0;
  auto A = [&](size_t bytes)->char*{
    char* p = ws + off; off = (off + bytes + 255) & ~(size_t)255; return p;
  };

  // ---- workspace layout ----
  u16* x_hi   = (u16*)A(BT*768L*2);          // reused later for s1/e1 family
  u16* x_lo   = (u16*)A(BT*768L*2);
  u16* Wx0f_hi= (u16*)A(1200L*768*2); u16* Wx0f_lo=(u16*)A(1200L*768*2);
  u16* Wx0b_hi= (u16*)A(1200L*768*2); u16* Wx0b_lo=(u16*)A(1200L*768*2);
  u16* Wr0_hi = (u16*)A(2L*1200*HP*2); u16* Wr0_lo=(u16*)A(2L*1200*HP*2);
  u16* Wx1f_hi= (u16*)A(1200L*800*2); u16* Wx1f_lo=(u16*)A(1200L*800*2);
  u16* Wx1b_hi= (u16*)A(1200L*800*2); u16* Wx1b_lo=(u16*)A(1200L*800*2);
  u16* Wr1_hi = (u16*)A(2L*1200*HP*2); u16* Wr1_lo=(u16*)A(2L*1200*HP*2);
  u16* Whw_hi = (u16*)A(800L*800*2);  u16* Whw_lo=(u16*)A(800L*800*2);
  u16* Ws_hi  = (u16*)A(150L*800*2);  u16* Ws_lo =(u16*)A(150L*800*2);
  u16* We_hi  = (u16*)A(150L*800*2);  u16* We_lo =(u16*)A(150L*800*2);
  u16* Ut_hi  = (u16*)A(1208L*160*2); u16* Ut_lo =(u16*)A(1208L*160*2);
  float* Zx   = (float*)A(2L*BT*G3*4);       // 39.3 MB (reused for tmp hi/lo)
  u32* init_hex = (u32*)A((long)HFRAG*4);
  u32* hbuf0  = (u32*)A(2L*T_*HFRAG*4);      // 13.6 MB sentinel-poll buffers
  u32* hbuf1  = (u32*)A(2L*T_*HFRAG*4);
  float* out0f= (float*)A((long)BT*H2*4);
  u16* out0_hi= (u16*)A((long)BT*H2*2); u16* out0_lo=(u16*)A((long)BT*H2*2);
  float* out1f= (float*)A((long)BT*H2*4);
  u16* out1_hi= (u16*)A((long)BT*H2*2); u16* out1_lo=(u16*)A((long)BT*H2*2);
  float* Gbuf = (float*)A((long)BT*H2*4);
  u16* cur_hi = (u16*)A((long)BT*H2*2); u16* cur_lo=(u16*)A((long)BT*H2*2);

  // overlays
  char* xreg = (char*)x_hi;                  // x dead after layer-0 proj GEMMs
  u16*   s1_hi = (u16*)xreg;
  u16*   s1_lo = (u16*)(xreg + 1310720);
  u16*   e1_hi = (u16*)(xreg + 2*1310720);
  u16*   e1_lo = (u16*)(xreg + 3*1310720);
  u16* tmp_hi = (u16*)Zx;                    // Zx dead after layer-1 LSTM
  u16* tmp_lo = tmp_hi + 32768L*160;
  float* Zx_f = Zx;
  float* Zx_b = Zx + (long)BT*G3;
  float* outp = (float*)d_out;

  // ---- transpose/convert jobs ----
  TJobs tj;
  auto setj=[&](int k,const float* in,int ld,int r0,int R,int Rp,int Cc,u16* oh,u16* ol){
    tj.j[k].in=in; tj.j[k].ld=ld; tj.j[k].r0=r0; tj.j[k].R=R; tj.j[k].Rpad=Rp;
    tj.j[k].Cc=Cc; tj.j[k].ohi=oh; tj.j[k].olo=ol;
  };
  const long WRD = 1200L*HP;
  setj(0,  W_f0,1200,  0,768,768,1200, Wx0f_hi,Wx0f_lo);
  setj(1,  W_f0,1200,768,400,HP ,1200, Wr0_hi, Wr0_lo);
  setj(2,  W_b0,1200,  0,768,768,1200, Wx0b_hi,Wx0b_lo);
  setj(3,  W_b0,1200,768,400,HP ,1200, Wr0_hi+WRD, Wr0_lo+WRD);
  setj(4,  W_f1,1200,  0,800,800,1200, Wx1f_hi,Wx1f_lo);
  setj(5,  W_f1,1200,800,400,HP ,1200, Wr1_hi, Wr1_lo);
  setj(6,  W_b1,1200,  0,800,800,1200, Wx1b_hi,Wx1b_lo);
  setj(7,  W_b1,1200,800,400,HP ,1200, Wr1_hi+WRD, Wr1_lo+WRD);
  setj(8,  W_hw, 800,  0,800,800, 800, Whw_hi,Whw_lo);
  setj(9,  W_s,  150,  0,800,800, 150, Ws_hi, Ws_lo);
  setj(10, W_e,  150,  0,800,800, 150, We_hi, We_lo);
  setj(11, U,   1208,  0,151,160,1208, Ut_hi, Ut_lo);

  // ---- pipeline ----
  hipMemsetAsync(hbuf0, 0xFF, 2L*T_*HFRAG*4, stream);
  hipMemsetAsync(hbuf1, 0xFF, 2L*T_*HFRAG*4, stream);
  k_cvt<<<4096,256,0,stream>>>(x, x_hi, x_lo, (long)BT*768, 1,1,1);
  k_tcvt<<<dim3(512,12),256,0,stream>>>(tj);
  k_init_hex<<<26,256,0,stream>>>(h0, init_hex);

  // layer 0 input projections
  k_gemm<0><<<dim3(19,64),256,0,stream>>>(x_hi,x_lo,768, Wx0f_hi,Wx0f_lo, b_f0, Zx_f, nullptr,nullptr, 1200,1200);
  k_gemm<0><<<dim3(19,64),256,0,stream>>>(x_hi,x_lo,768, Wx0b_hi,Wx0b_lo, b_b0, Zx_b, nullptr,nullptr, 1200,1200);
  k_lstm<<<dim3(NS,2),256,0,stream>>>(Zx, Wr0_hi,Wr0_lo, c0, init_hex, hbuf0,
                                      out0f, out0_hi, out0_lo);
  // layer 1 input projections (input = concat(xf,xb) of layer 0)
  k_gemm<0><<<dim3(19,64),256,0,stream>>>(out0_hi,out0_lo,800, Wx1f_hi,Wx1f_lo, b_f1, Zx_f, nullptr,nullptr, 1200,1200);
  k_gemm<0><<<dim3(19,64),256,0,stream>>>(out0_hi,out0_lo,800, Wx1b_hi,Wx1b_lo, b_b1, Zx_b, nullptr,nullptr, 1200,1200);
  k_lstm<<<dim3(NS,2),256,0,stream>>>(Zx, Wr1_hi,Wr1_lo, c0, init_hex, hbuf1,
                                      out1f, out1_hi, out1_lo);
  // highway: gate = sigmoid(out1 @ W_hw + b_hw); cur = g*out1 + (1-g)*out0
  k_gemm<1><<<dim3(13,64),256,0,stream>>>(out1_hi,out1_lo,800, Whw_hi,Whw_lo, b_hw, Gbuf, nullptr,nullptr, 800,800);
  k_highway<<<4096,256,0,stream>>>(Gbuf, out1f, out0f, cur_hi, cur_lo, (long)BT*H2);
  // start/end projections -> s1/e1 bf16 hi/lo with appended 1.0 col, K-pad 160
  k_gemm<2><<<dim3(3,64),256,0,stream>>>(cur_hi,cur_lo,800, Ws_hi,Ws_lo, b_s, nullptr, s1_hi,s1_lo, 150,160);
  k_gemm<2><<<dim3(3,64),256,0,stream>>>(cur_hi,cur_lo,800, We_hi,We_lo, b_e, nullptr, e1_hi,e1_lo, 150,160);
  // biaffine stage 1: tmp[b,x,c,j] = sum_i s1[b,x,i] U[i,c,j]  (bf16 hi/lo out)
  hipMemsetAsync(tmp_hi, 0, 32768L*160*2*2, stream);   // zero incl. j=151..159 pad
  k_gemm<3><<<dim3(19,64),256,0,stream>>>(s1_hi,s1_lo,160, Ut_hi,Ut_lo, nullptr, nullptr, tmp_hi,tmp_lo, 1208,1208);
  // biaffine stage 2: out[b,x,y,c] = sum_j tmp[b,x,c,j] e1[b,y,j]
  k_gemm<4><<<dim3(4,32,16),256,0,stream>>>(tmp_hi,tmp_lo,160, e1_hi,e1_lo, nullptr, outp, nullptr,nullptr, 256,256);
}

// Round 7
// 3895.504 us; speedup vs baseline: 1.3025x; 1.3025x over previous
//
#include <hip/hip_runtime.h>
#include <stdint.h>

// ---------------------------------------------------------------------------
// BiaffineNER: 2-layer biLSTM (coupled gates) + highway + biaffine span scores
// B=16 T=256 D=768 H=400 F=150 C=8.
//
// Round 6 (resubmit; prior attempt hit GPU-acquisition timeout, never ran):
// round-3 flag protocol (proven 3034us) minus its serializations.
//  * Per-WAVE flags: each wave stores flag after s_waitcnt vmcnt(0) on its own
//    h-stores; exports after the flag; second __syncthreads deleted (zlds
//    double-buffered; wave-3 read-done flags guard h dbuf reuse).
//  * MODE 5 GEMM: f+b projection weights adjacent -> one N=2400 dispatch/layer.
//  * MODE 4 GEMM: float4 epilogue stores (c index is i-contiguous).
// Lesson from R5 (regression): poll cheap flag lines, load data once — bulk
// data-reload polling congests L3 and slows the producers it waits on.
// ---------------------------------------------------------------------------

#define B_  16
#define T_  256
#define D_  768
#define H_  400
#define HP  416      // K-padded H (13 tiles of 32)
#define G3  1200     // 3H
#define H2  800      // 2H
#define NS  20       // weight slices per direction
#define HS  20       // hidden units per slice
#define BT  4096     // B*T
#define HFRAG 6656   // u32s per h buffer: 13 kt * 512
#define NFLG 80      // flags per (q,dir): NS WGs x 4 waves

using bf16x8 = __attribute__((ext_vector_type(8))) short;
using f32x4  = __attribute__((ext_vector_type(4))) float;
typedef unsigned short u16;
typedef unsigned int   u32;
typedef unsigned long long u64;

__device__ __forceinline__ u16 bf16_rne(float v){
  u32 u = __builtin_bit_cast(u32, v);
  u32 r = u + 0x7fffu + ((u >> 16) & 1u);
  return (u16)(r >> 16);
}
__device__ __forceinline__ void splitf(float v, u16 &hi, u16 &lo){
  u16 h = bf16_rne(v);
  float hf = __builtin_bit_cast(float, (u32)h << 16);
  hi = h;
  lo = bf16_rne(v - hf);
}

// --------------------------- elementwise fp32 -> bf16 hi/lo -----------------
__global__ void k_cvt(const float* __restrict__ in, u16* __restrict__ ohi,
                      u16* __restrict__ olo, long rows, int ld, int cr, int cp){
  long total = rows * (long)cp;
  for (long i = (long)blockIdx.x*blockDim.x + threadIdx.x; i < total;
       i += (long)gridDim.x*blockDim.x){
    long rr = i / cp; int j = (int)(i - rr*cp);
    float v = (j < cr) ? in[rr*(long)ld + j] : 0.f;
    u16 h,l; splitf(v,h,l);
    ohi[i] = h; olo[i] = l;
  }
}

// --------------------------- transpose + convert ----------------------------
struct TJob { const float* in; int ld, r0, R, Rpad, Cc; u16* ohi; u16* olo; };
struct TJobs { TJob j[12]; };
__global__ void k_tcvt(TJobs js){
  TJob jb = js.j[blockIdx.y];
  long total = (long)jb.Cc * jb.Rpad;
  for (long i = (long)blockIdx.x*blockDim.x + threadIdx.x; i < total;
       i += (long)gridDim.x*blockDim.x){
    long c = i / jb.Rpad; int rr = (int)(i - c*jb.Rpad);
    float v = (rr < jb.R) ? jb.in[(long)(jb.r0+rr)*jb.ld + c] : 0.f;
    u16 h,l; splitf(v,h,l);
    jb.ohi[i] = h; jb.olo[i] = l;
  }
}

// --------------------------- generic MFMA GEMM ------------------------------
// C[M x N] = A[M x Ka] * B^T[N x Ka]  (split-bf16 hi/lo, 3-term).
// MODE 1: out = sigmoid(acc + bias)
// MODE 2: s1/e1 build -> bf16 hi/lo [M][160]: col<150 acc+bias; 150: 1.0; else 0
// MODE 3: biaffine stage1 -> bf16 hi/lo: col n -> (c=n/151, j=n%151) at
//         [(row*8+c)*160 + j]
// MODE 4: biaffine stage2 (per-z batch): A+=z*2048*Ka, B+=z*256*Ka,
//         out[((z*256 + row/8)*256 + col)*8 + (row&7)] = acc  (float4 stores)
// MODE 5: merged f/b projection: col<1200 -> out[row*1200+col] (+bias),
//         col>=1200 -> out[BT*1200 + row*1200 + col-1200] (+bias2)
template<int MODE>
__global__ __launch_bounds__(256)
void k_gemm(const u16* __restrict__ Ahi, const u16* __restrict__ Alo, int Ka,
            const u16* __restrict__ Bhi, const u16* __restrict__ Blo,
            const float* __restrict__ bias, const float* __restrict__ bias2,
            float* __restrict__ out,
            u16* __restrict__ ohi, u16* __restrict__ olo,
            int Nreal, int Nstore)
{
  const int lane = threadIdx.x & 63, wave = threadIdx.x >> 6;
  long za = 0, zb = 0;
  if (MODE == 4){ za = (long)blockIdx.z*2048*Ka; zb = (long)blockIdx.z*256*Ka; }
  const u16* Ah = Ahi + za; const u16* Al = Alo + za;
  const u16* Bh = Bhi + zb; const u16* Bl = Blo + zb;

  const int row0 = blockIdx.y*64 + wave*16;
  const int col0 = blockIdx.x*64;
  const int r    = row0 + (lane & 15);
  const int kofs = (lane >> 4) * 8;

  const f32x4 vz = {0.f,0.f,0.f,0.f};
  f32x4 acc_hh[4], acc_x[4];
  #pragma unroll
  for (int nt=0; nt<4; ++nt){ acc_hh[nt]=vz; acc_x[nt]=vz; }
  const bf16x8 bz = {0,0,0,0,0,0,0,0};

  const int ktn = Ka >> 5;
  for (int kt=0; kt<ktn; ++kt){
    const int k0 = kt*32 + kofs;
    bf16x8 ah = *(const bf16x8*)(Ah + (long)r*Ka + k0);
    bf16x8 al = *(const bf16x8*)(Al + (long)r*Ka + k0);
    #pragma unroll
    for (int nt=0; nt<4; ++nt){
      int cc = col0 + nt*16 + (lane & 15);
      bf16x8 bh = bz, bl = bz;
      if (cc < Nreal){
        bh = *(const bf16x8*)(Bh + (long)cc*Ka + k0);
        bl = *(const bf16x8*)(Bl + (long)cc*Ka + k0);
      }
      acc_x[nt]  = __builtin_amdgcn_mfma_f32_16x16x32_bf16(al, bh, acc_x[nt], 0,0,0);
      acc_x[nt]  = __builtin_amdgcn_mfma_f32_16x16x32_bf16(ah, bl, acc_x[nt], 0,0,0);
      acc_hh[nt] = __builtin_amdgcn_mfma_f32_16x16x32_bf16(ah, bh, acc_hh[nt], 0,0,0);
    }
  }

  #pragma unroll
  for (int nt=0; nt<4; ++nt){
    int ocol = col0 + nt*16 + (lane & 15);
    if (ocol >= Nstore) continue;
    if (MODE == 4){
      int rbase = row0 + (lane>>4)*4;
      int xx = rbase >> 3, cb = rbase & 7;        // cb in {0,4}
      float4 vv;
      vv.x = acc_hh[nt][0] + acc_x[nt][0];
      vv.y = acc_hh[nt][1] + acc_x[nt][1];
      vv.z = acc_hh[nt][2] + acc_x[nt][2];
      vv.w = acc_hh[nt][3] + acc_x[nt][3];
      *(float4*)(out + ((((long)blockIdx.z*256 + xx)*256 + ocol)<<3) + cb) = vv;
      continue;
    }
    #pragma unroll
    for (int i=0; i<4; ++i){
      int orow = row0 + (lane>>4)*4 + i;
      float v = acc_hh[nt][i] + acc_x[nt][i];
      if (MODE == 1){
        float t = v + bias[ocol];
        out[(long)orow*Nstore + ocol] = 1.f/(1.f + expf(-t));
      } else if (MODE == 2){
        float t;
        if (ocol < 150) t = v + bias[ocol];
        else            t = (ocol == 150) ? 1.f : 0.f;
        u16 h,l; splitf(t,h,l);
        long idx = (long)orow*160 + ocol;
        ohi[idx] = h; olo[idx] = l;
      } else if (MODE == 3){
        int c = ocol/151, j = ocol - c*151;
        u16 h,l; splitf(v,h,l);
        long idx = ((long)orow*8 + c)*160 + j;
        ohi[idx] = h; olo[idx] = l;
      } else if (MODE == 5){
        float t = v + (ocol < 1200 ? bias[ocol] : bias2[ocol-1200]);
        long dst = (ocol < 1200)
                 ? ((long)orow*1200 + ocol)
                 : ((long)BT*1200 + (long)orow*1200 + (ocol-1200));
        out[dst] = t;
      }
    }
  }
}

// --------------------------- h-state init (fragment order) ------------------
// h_ex: [2 dir][2 buf][HFRAG] u32. buf 1 <- h0 frag-order, buf 0 <- 0.
__global__ void k_init_hex(const float* __restrict__ h0, u32* __restrict__ h_ex){
  const int total = 2*2*HFRAG;
  for (int i = blockIdx.x*blockDim.x + threadIdx.x; i < total;
       i += gridDim.x*blockDim.x){
    int j = i % HFRAG;
    int buf = (i / HFRAG) & 1;
    int kt = j >> 9, rr = j & 511;
    int p = rr >> 7, rem = rr & 127, l = rem >> 1, odd = rem & 1;
    int sub = l >> 4;
    int k = kt*32 + sub*8 + p*2 + odd;
    u32 v = 0;
    if (buf == 1 && k < H_){ u16 h,lo; splitf(h0[k],h,lo); v = ((u32)h<<16)|lo; }
    h_ex[i] = v;
  }
}

// --------------------------- LSTM scan kernel -------------------------------
// grid = (NS, 2 dirs), 256 threads (4 waves, 1 wave/SIMD).
// flags: [T][2][NFLG] u32 (memset 0). Per-wave flag = "published h(q) AND
// finished reading h(q-1)" -> guards both data-ready and dbuf reuse.
__global__ __launch_bounds__(256, 1)
void k_lstm(const float* __restrict__ Zx,                // [2][BT][G3]
            const u16* __restrict__ Wrhi, const u16* __restrict__ Wrlo, // [2][G3][HP]
            const float* __restrict__ c0,
            u32* h_ex,                                   // [2][2][HFRAG]
            u32* flags,
            float* __restrict__ outf,                    // [BT][H2]
            u16* __restrict__ out_hi, u16* __restrict__ out_lo)
{
  const int s = blockIdx.x, dir = blockIdx.y;
  const int tid = threadIdx.x, lane = tid & 63, wave = tid >> 6;
  const int u0 = s*HS;
  const int kofs = (lane >> 4) * 8;
  const bf16x8 bz = {0,0,0,0,0,0,0,0};
  const f32x4 vz = {0.f,0.f,0.f,0.f};

  // ---- persistent W fragments (B operand), cols = slice's 60 gate columns --
  const int lc = wave*16 + (lane & 15);          // local col 0..63 (>=60 pad)
  const bool colok = lc < 3*HS;
  int gcol = 0;
  if (colok){ int gg = lc/HS, idx = lc - gg*HS; gcol = gg*400 + u0 + idx; }
  const u16* wph = Wrhi + ((long)dir*G3 + gcol)*HP;
  const u16* wpl = Wrlo + ((long)dir*G3 + gcol)*HP;
  bf16x8 bh[13], bl[13];
  #pragma unroll
  for (int kt=0; kt<13; ++kt){
    bh[kt] = colok ? *(const bf16x8*)(wph + kt*32 + kofs) : bz;
    bl[kt] = colok ? *(const bf16x8*)(wpl + kt*32 + kofs) : bz;
  }

  // ---- update mapping: tid<160: b = tid/10, units ku=u0+2*(tid%10), ku+1 ----
  const bool upd = (tid < 160);
  const int b_a = tid/10, up_a = tid - (tid/10)*10;
  const int ku  = u0 + 2*up_a;                   // even unit index (global k)
  float c_a0 = 0.f, c_a1 = 0.f;
  if (upd){ c_a0 = c0[ku]; c_a1 = c0[ku+1]; }

  const float* zxd = Zx + (long)dir*BT*G3;
  const long zbase = (long)b_a*T_*G3 + ku;

  u32* hex_d = h_ex + (long)dir*2*HFRAG;
  // producer u32 slots for (b_a, ku, ku+1):
  const int pkt = ku >> 5, pk = ku & 31;
  const int psub = pk >> 3, pp = (pk & 7) >> 1;
  const int pslot = pkt*256 + pp*64 + (psub*16 + b_a);   // u64-pair index

  __shared__ float zlds[2][16][64];

  for (int q=0; q<T_; ++q){
    const int t = dir ? (T_-1-q) : q;

    // prefetch Zx (overlaps the poll)
    float2 zxi = {0.f,0.f}, zxj = {0.f,0.f}, zxo = {0.f,0.f};
    if (upd){
      const float* zp = zxd + zbase + (long)t*G3;
      zxi = *(const float2*)(zp);
      zxj = *(const float2*)(zp + 400);
      zxo = *(const float2*)(zp + 800);
    }

    // wait for all 80 per-wave flags of step q-1 (5 cache lines)
    if (q > 0){
      const u32* f = flags + ((q-1)*2 + dir)*NFLG;
      while (true){
        u32 va = __hip_atomic_load(f + lane, __ATOMIC_RELAXED,
                                   __HIP_MEMORY_SCOPE_AGENT);
        u32 vb = (lane < NFLG-64)
               ? __hip_atomic_load(f + 64 + lane, __ATOMIC_RELAXED,
                                   __HIP_MEMORY_SCOPE_AGENT)
               : 1u;
        if (__all((va != 0u) & (vb != 0u))) break;
        __builtin_amdgcn_s_sleep(1);
      }
    }

    // load h_{q-1} fragments once: coalesced u64 agent loads, shift/mask unpack
    const u64* hx = (const u64*)(hex_d + ((q&1)^1)*HFRAG);
    bf16x8 ah[13], al[13];
    #pragma unroll
    for (int kt=0; kt<13; ++kt){
      #pragma unroll
      for (int p=0; p<4; ++p){
        u64 d = __hip_atomic_load(hx + kt*256 + p*64 + lane, __ATOMIC_RELAXED,
                                  __HIP_MEMORY_SCOPE_AGENT);
        u32 w0 = (u32)d, w1 = (u32)(d >> 32);
        ah[kt][2*p]   = (short)(w0 >> 16); al[kt][2*p]   = (short)(w0 & 0xffffu);
        ah[kt][2*p+1] = (short)(w1 >> 16); al[kt][2*p+1] = (short)(w1 & 0xffffu);
      }
    }

    // z_slice = h @ Wslice (3 independent MFMA chains)
    f32x4 a0 = vz, a1 = vz, a2 = vz;
    #pragma unroll
    for (int kt=0; kt<13; ++kt){
      a0 = __builtin_amdgcn_mfma_f32_16x16x32_bf16(al[kt], bh[kt], a0, 0,0,0);
      a1 = __builtin_amdgcn_mfma_f32_16x16x32_bf16(ah[kt], bl[kt], a1, 0,0,0);
      a2 = __builtin_amdgcn_mfma_f32_16x16x32_bf16(ah[kt], bh[kt], a2, 0,0,0);
    }
    #pragma unroll
    for (int i=0; i<4; ++i)
      zlds[q&1][(lane>>4)*4 + i][lc] = a0[i] + a1[i] + a2[i];
    __syncthreads();   // the ONLY barrier: zlds[q&1] ready (dbuf makes it safe)

    // gate math + h publish
    if (upd){
      const int uu = 2*up_a;
      float vi0 = zlds[q&1][b_a][uu]          + zxi.x;
      float vj0 = zlds[q&1][b_a][HS + uu]     + zxj.x;
      float vo0 = zlds[q&1][b_a][2*HS + uu]   + zxo.x;
      float vi1 = zlds[q&1][b_a][uu+1]        + zxi.y;
      float vj1 = zlds[q&1][b_a][HS + uu+1]   + zxj.y;
      float vo1 = zlds[q&1][b_a][2*HS + uu+1] + zxo.y;
      float ig0 = 1.f/(1.f + expf(-vi0));
      c_a0 = (1.f - ig0)*c_a0 + ig0*tanhf(vj0);
      float hh0 = tanhf(c_a0) * (1.f/(1.f + expf(-vo0)));
      float ig1 = 1.f/(1.f + expf(-vi1));
      c_a1 = (1.f - ig1)*c_a1 + ig1*tanhf(vj1);
      float hh1 = tanhf(c_a1) * (1.f/(1.f + expf(-vo1)));
      u16 h0h,h0l,h1h,h1l;
      splitf(hh0,h0h,h0l); splitf(hh1,h1h,h1l);
      u32* dstb = hex_d + (q&1)*HFRAG;
      __hip_atomic_store(dstb + 2*pslot,     (((u32)h0h)<<16)|h0l,
                         __ATOMIC_RELAXED, __HIP_MEMORY_SCOPE_AGENT);
      __hip_atomic_store(dstb + 2*pslot + 1, (((u32)h1h)<<16)|h1l,
                         __ATOMIC_RELAXED, __HIP_MEMORY_SCOPE_AGENT);
      // wave-local drain of the h stores, then this wave's flag
      asm volatile("s_waitcnt vmcnt(0)" ::: "memory");
      if (lane == 0)
        __hip_atomic_store(flags + (q*2 + dir)*NFLG + s*4 + wave, 1u,
                           __ATOMIC_RELAXED, __HIP_MEMORY_SCOPE_AGENT);
      // exports AFTER the flag: drain overlaps next step's poll
      long o = ((long)b_a*T_ + t)*H2 + dir*H_ + ku;
      float2 of = {hh0, hh1};
      *(float2*)(outf + o) = of;
      *(u32*)(out_hi + o) = (((u32)h1h)<<16) | h0h;
      *(u32*)(out_lo + o) = (((u32)h1l)<<16) | h0l;
    } else {
      // non-producer wave: its flag certifies "done reading h(q-1)"
      asm volatile("s_waitcnt vmcnt(0)" ::: "memory");
      if (lane == 0)
        __hip_atomic_store(flags + (q*2 + dir)*NFLG + s*4 + wave, 1u,
                           __ATOMIC_RELAXED, __HIP_MEMORY_SCOPE_AGENT);
    }
  }
}

// --------------------------- highway combine --------------------------------
__global__ void k_highway(const float* __restrict__ G, const float* __restrict__ o1,
                          const float* __restrict__ o0,
                          u16* __restrict__ chi, u16* __restrict__ clo, long n){
  for (long i = (long)blockIdx.x*blockDim.x + threadIdx.x; i < n;
       i += (long)gridDim.x*blockDim.x){
    float g = G[i];
    float v = g*o1[i] + (1.f - g)*o0[i];
    u16 h,l; splitf(v,h,l);
    chi[i] = h; clo[i] = l;
  }
}

// ---------------------------------------------------------------------------
extern "C" void kernel_launch(void* const* d_in, const int* in_sizes, int n_in,
                              void* d_out, int out_size, void* d_ws, size_t ws_size,
                              hipStream_t stream)
{
  (void)in_sizes; (void)n_in; (void)out_size; (void)ws_size;
  const float* x    = (const float*)d_in[0];
  const float* W_f0 = (const float*)d_in[1];
  const float* b_f0 = (const float*)d_in[2];
  const float* W_b0 = (const float*)d_in[3];
  const float* b_b0 = (const float*)d_in[4];
  const float* W_f1 = (const float*)d_in[5];
  const float* b_f1 = (const float*)d_in[6];
  const float* W_b1 = (const float*)d_in[7];
  const float* b_b1 = (const float*)d_in[8];
  const float* h0   = (const float*)d_in[9];
  const float* c0   = (const float*)d_in[10];
  const float* W_hw = (const float*)d_in[11];
  const float* b_hw = (const float*)d_in[12];
  const float* W_s  = (const float*)d_in[13];
  const float* b_s  = (const float*)d_in[14];
  const float* W_e  = (const float*)d_in[15];
  const float* b_e  = (const float*)d_in[16];
  const float* U    = (const float*)d_in[17];

  char* ws = (char*)d_ws;
  size_t off = 0;
  auto A = [&](size_t bytes)->char*{
    char* p = ws + off; off = (off + bytes + 255) & ~(size_t)255; return p;
  };

  // ---- workspace layout ----
  u16* x_hi   = (u16*)A(BT*768L*2);          // reused later for s1/e1 family
  u16* x_lo   = (u16*)A(BT*768L*2);
  u16* Wx0_hi = (u16*)A(2400L*768*2);        // rows 0..1199 = f, 1200..2399 = b
  u16* Wx0_lo = (u16*)A(2400L*768*2);
  u16* Wr0_hi = (u16*)A(2L*1200*HP*2); u16* Wr0_lo=(u16*)A(2L*1200*HP*2);
  u16* Wx1_hi = (u16*)A(2400L*800*2);
  u16* Wx1_lo = (u16*)A(2400L*800*2);
  u16* Wr1_hi = (u16*)A(2L*1200*HP*2); u16* Wr1_lo=(u16*)A(2L*1200*HP*2);
  u16* Whw_hi = (u16*)A(800L*800*2);  u16* Whw_lo=(u16*)A(800L*800*2);
  u16* Ws_hi  = (u16*)A(150L*800*2);  u16* Ws_lo =(u16*)A(150L*800*2);
  u16* We_hi  = (u16*)A(150L*800*2);  u16* We_lo =(u16*)A(150L*800*2);
  u16* Ut_hi  = (u16*)A(1208L*160*2); u16* Ut_lo =(u16*)A(1208L*160*2);
  float* Zx   = (float*)A(2L*BT*G3*4);       // 39.3 MB (reused for tmp hi/lo)
  u32* h_ex   = (u32*)A(2L*2*HFRAG*4);
  u32* flags  = (u32*)A(2L*T_*2*NFLG*4);     // [layer][T][dir][NFLG]
  float* out0f= (float*)A((long)BT*H2*4);
  u16* out0_hi= (u16*)A((long)BT*H2*2); u16* out0_lo=(u16*)A((long)BT*H2*2);
  float* out1f= (float*)A((long)BT*H2*4);
  u16* out1_hi= (u16*)A((long)BT*H2*2); u16* out1_lo=(u16*)A((long)BT*H2*2);
  float* Gbuf = (float*)A((long)BT*H2*4);
  u16* cur_hi = (u16*)A((long)BT*H2*2); u16* cur_lo=(u16*)A((long)BT*H2*2);

  // overlays
  char* xreg = (char*)x_hi;                  // x dead after layer-0 proj GEMM
  u16*   s1_hi = (u16*)xreg;
  u16*   s1_lo = (u16*)(xreg + 1310720);
  u16*   e1_hi = (u16*)(xreg + 2*1310720);
  u16*   e1_lo = (u16*)(xreg + 3*1310720);
  u16* tmp_hi = (u16*)Zx;                    // Zx dead after layer-1 LSTM
  u16* tmp_lo = tmp_hi + 32768L*160;
  float* outp = (float*)d_out;

  // ---- transpose/convert jobs ----
  TJobs tj;
  auto setj=[&](int k,const float* in,int ld,int r0,int R,int Rp,int Cc,u16* oh,u16* ol){
    tj.j[k].in=in; tj.j[k].ld=ld; tj.j[k].r0=r0; tj.j[k].R=R; tj.j[k].Rpad=Rp;
    tj.j[k].Cc=Cc; tj.j[k].ohi=oh; tj.j[k].olo=ol;
  };
  const long WRD = 1200L*HP;
  setj(0,  W_f0,1200,  0,768,768,1200, Wx0_hi, Wx0_lo);
  setj(1,  W_b0,1200,  0,768,768,1200, Wx0_hi+1200L*768, Wx0_lo+1200L*768);
  setj(2,  W_f0,1200,768,400,HP ,1200, Wr0_hi, Wr0_lo);
  setj(3,  W_b0,1200,768,400,HP ,1200, Wr0_hi+WRD, Wr0_lo+WRD);
  setj(4,  W_f1,1200,  0,800,800,1200, Wx1_hi, Wx1_lo);
  setj(5,  W_b1,1200,  0,800,800,1200, Wx1_hi+1200L*800, Wx1_lo+1200L*800);
  setj(6,  W_f1,1200,800,400,HP ,1200, Wr1_hi, Wr1_lo);
  setj(7,  W_b1,1200,800,400,HP ,1200, Wr1_hi+WRD, Wr1_lo+WRD);
  setj(8,  W_hw, 800,  0,800,800, 800, Whw_hi,Whw_lo);
  setj(9,  W_s,  150,  0,800,800, 150, Ws_hi, Ws_lo);
  setj(10, W_e,  150,  0,800,800, 150, We_hi, We_lo);
  setj(11, U,   1208,  0,151,160,1208, Ut_hi, Ut_lo);

  // ---- pipeline ----
  hipMemsetAsync(flags, 0, 2L*T_*2*NFLG*4, stream);
  k_cvt<<<4096,256,0,stream>>>(x, x_hi, x_lo, (long)BT*768, 1,1,1);
  k_tcvt<<<dim3(512,12),256,0,stream>>>(tj);
  k_init_hex<<<104,256,0,stream>>>(h0, h_ex);

  // layer 0: merged f+b input projection (one dispatch, A read once)
  k_gemm<5><<<dim3(38,64),256,0,stream>>>(x_hi,x_lo,768, Wx0_hi,Wx0_lo,
                                          b_f0, b_b0, Zx, nullptr,nullptr, 2400,2400);
  k_lstm<<<dim3(NS,2),256,0,stream>>>(Zx, Wr0_hi,Wr0_lo, c0, h_ex, flags,
                                      out0f, out0_hi, out0_lo);
  // layer 1: merged projection (input = concat(xf,xb) of layer 0)
  k_gemm<5><<<dim3(38,64),256,0,stream>>>(out0_hi,out0_lo,800, Wx1_hi,Wx1_lo,
                                          b_f1, b_b1, Zx, nullptr,nullptr, 2400,2400);
  k_init_hex<<<104,256,0,stream>>>(h0, h_ex);
  k_lstm<<<dim3(NS,2),256,0,stream>>>(Zx, Wr1_hi,Wr1_lo, c0, h_ex,
                                      flags + (long)T_*2*NFLG,
                                      out1f, out1_hi, out1_lo);
  // highway: gate = sigmoid(out1 @ W_hw + b_hw); cur = g*out1 + (1-g)*out0
  k_gemm<1><<<dim3(13,64),256,0,stream>>>(out1_hi,out1_lo,800, Whw_hi,Whw_lo,
                                          b_hw, nullptr, Gbuf, nullptr,nullptr, 800,800);
  k_highway<<<4096,256,0,stream>>>(Gbuf, out1f, out0f, cur_hi, cur_lo, (long)BT*H2);
  // start/end projections -> s1/e1 bf16 hi/lo with appended 1.0 col, K-pad 160
  k_gemm<2><<<dim3(3,64),256,0,stream>>>(cur_hi,cur_lo,800, Ws_hi,Ws_lo,
                                         b_s, nullptr, nullptr, s1_hi,s1_lo, 150,160);
  k_gemm<2><<<dim3(3,64),256,0,stream>>>(cur_hi,cur_lo,800, We_hi,We_lo,
                                         b_e, nullptr, nullptr, e1_hi,e1_lo, 150,160);
  // biaffine stage 1: tmp[b,x,c,j] = sum_i s1[b,x,i] U[i,c,j]  (bf16 hi/lo out)
  hipMemsetAsync(tmp_hi, 0, 32768L*160*2*2, stream);   // zero incl. j=151..159 pad
  k_gemm<3><<<dim3(19,64),256,0,stream>>>(s1_hi,s1_lo,160, Ut_hi,Ut_lo,
                                          nullptr, nullptr, nullptr, tmp_hi,tmp_lo, 1208,1208);
  // biaffine stage 2: out[b,x,y,c] = sum_j tmp[b,x,c,j] e1[b,y,j]
  k_gemm<4><<<dim3(4,32,16),256,0,stream>>>(tmp_hi,tmp_lo,160, e1_hi,e1_lo,
                                            nullptr, nullptr, outp, nullptr,nullptr, 256,256);
}

// Round 8
// 2565.122 us; speedup vs baseline: 1.9780x; 1.5186x over previous
//
#include <hip/hip_runtime.h>
#include <stdint.h>

// ---------------------------------------------------------------------------
// BiaffineNER: 2-layer biLSTM (coupled gates) + highway + biaffine span scores
// B=16 T=256 D=768 H=400 F=150 C=8.
//
// Round 8: R3 sync protocol restored EXACTLY (best measured: 4.3us/step) +
// bf16-hi-only h exchange:
//  * h published as packed 2x bf16-hi per u32 (13.3KB/buffer, half of R3);
//    consumer: 52 coalesced u32 agent loads, zero-op bit_cast unpack,
//    2 MFMA chains (h_hi x W_hi + h_hi x W_lo). c stays fp32 in registers;
//    exports stay split-precision (only the recurrent z_h path is rounded).
//  * exports moved after the per-WG flag (off barrier-2's drain).
//  * GEMM tail keeps R7's merged MODE5 projections + float4 MODE4 stores.
// Lessons: R5 (bulk data-reload polling) and R7 (80 per-wave flags) both
// regressed — keep sync-line stores minimal, drain via __syncthreads.
// ---------------------------------------------------------------------------

#define B_  16
#define T_  256
#define D_  768
#define H_  400
#define HP  416      // K-padded H (13 tiles of 32)
#define G3  1200     // 3H
#define H2  800      // 2H
#define NS  20       // weight slices per direction
#define HS  20       // hidden units per slice
#define BT  4096     // B*T
#define HFRAG 3328   // u32s per h buffer: 13 kt * 4 p * 64 lanes (hi-only)

using bf16x8 = __attribute__((ext_vector_type(8))) short;
using f32x4  = __attribute__((ext_vector_type(4))) float;
using u32x4  = __attribute__((ext_vector_type(4))) unsigned int;
typedef unsigned short u16;
typedef unsigned int   u32;
typedef unsigned long long u64;

__device__ __forceinline__ u16 bf16_rne(float v){
  u32 u = __builtin_bit_cast(u32, v);
  u32 r = u + 0x7fffu + ((u >> 16) & 1u);
  return (u16)(r >> 16);
}
__device__ __forceinline__ void splitf(float v, u16 &hi, u16 &lo){
  u16 h = bf16_rne(v);
  float hf = __builtin_bit_cast(float, (u32)h << 16);
  hi = h;
  lo = bf16_rne(v - hf);
}

// --------------------------- elementwise fp32 -> bf16 hi/lo -----------------
__global__ void k_cvt(const float* __restrict__ in, u16* __restrict__ ohi,
                      u16* __restrict__ olo, long rows, int ld, int cr, int cp){
  long total = rows * (long)cp;
  for (long i = (long)blockIdx.x*blockDim.x + threadIdx.x; i < total;
       i += (long)gridDim.x*blockDim.x){
    long rr = i / cp; int j = (int)(i - rr*cp);
    float v = (j < cr) ? in[rr*(long)ld + j] : 0.f;
    u16 h,l; splitf(v,h,l);
    ohi[i] = h; olo[i] = l;
  }
}

// --------------------------- transpose + convert ----------------------------
struct TJob { const float* in; int ld, r0, R, Rpad, Cc; u16* ohi; u16* olo; };
struct TJobs { TJob j[12]; };
__global__ void k_tcvt(TJobs js){
  TJob jb = js.j[blockIdx.y];
  long total = (long)jb.Cc * jb.Rpad;
  for (long i = (long)blockIdx.x*blockDim.x + threadIdx.x; i < total;
       i += (long)gridDim.x*blockDim.x){
    long c = i / jb.Rpad; int rr = (int)(i - c*jb.Rpad);
    float v = (rr < jb.R) ? jb.in[(long)(jb.r0+rr)*jb.ld + c] : 0.f;
    u16 h,l; splitf(v,h,l);
    jb.ohi[i] = h; jb.olo[i] = l;
  }
}

// --------------------------- generic MFMA GEMM ------------------------------
// C[M x N] = A[M x Ka] * B^T[N x Ka]  (split-bf16 hi/lo, 3-term).
// MODE 1: out = sigmoid(acc + bias)
// MODE 2: s1/e1 build -> bf16 hi/lo [M][160]: col<150 acc+bias; 150: 1.0; else 0
// MODE 3: biaffine stage1 -> bf16 hi/lo: col n -> (c=n/151, j=n%151) at
//         [(row*8+c)*160 + j]
// MODE 4: biaffine stage2 (per-z batch): A+=z*2048*Ka, B+=z*256*Ka,
//         out[((z*256 + row/8)*256 + col)*8 + (row&7)] = acc  (float4 stores)
// MODE 5: merged f/b projection: col<1200 -> out[row*1200+col] (+bias),
//         col>=1200 -> out[BT*1200 + row*1200 + col-1200] (+bias2)
template<int MODE>
__global__ __launch_bounds__(256)
void k_gemm(const u16* __restrict__ Ahi, const u16* __restrict__ Alo, int Ka,
            const u16* __restrict__ Bhi, const u16* __restrict__ Blo,
            const float* __restrict__ bias, const float* __restrict__ bias2,
            float* __restrict__ out,
            u16* __restrict__ ohi, u16* __restrict__ olo,
            int Nreal, int Nstore)
{
  const int lane = threadIdx.x & 63, wave = threadIdx.x >> 6;
  long za = 0, zb = 0;
  if (MODE == 4){ za = (long)blockIdx.z*2048*Ka; zb = (long)blockIdx.z*256*Ka; }
  const u16* Ah = Ahi + za; const u16* Al = Alo + za;
  const u16* Bh = Bhi + zb; const u16* Bl = Blo + zb;

  const int row0 = blockIdx.y*64 + wave*16;
  const int col0 = blockIdx.x*64;
  const int r    = row0 + (lane & 15);
  const int kofs = (lane >> 4) * 8;

  const f32x4 vz = {0.f,0.f,0.f,0.f};
  f32x4 acc_hh[4], acc_x[4];
  #pragma unroll
  for (int nt=0; nt<4; ++nt){ acc_hh[nt]=vz; acc_x[nt]=vz; }
  const bf16x8 bz = {0,0,0,0,0,0,0,0};

  const int ktn = Ka >> 5;
  for (int kt=0; kt<ktn; ++kt){
    const int k0 = kt*32 + kofs;
    bf16x8 ah = *(const bf16x8*)(Ah + (long)r*Ka + k0);
    bf16x8 al = *(const bf16x8*)(Al + (long)r*Ka + k0);
    #pragma unroll
    for (int nt=0; nt<4; ++nt){
      int cc = col0 + nt*16 + (lane & 15);
      bf16x8 bh = bz, bl = bz;
      if (cc < Nreal){
        bh = *(const bf16x8*)(Bh + (long)cc*Ka + k0);
        bl = *(const bf16x8*)(Bl + (long)cc*Ka + k0);
      }
      acc_x[nt]  = __builtin_amdgcn_mfma_f32_16x16x32_bf16(al, bh, acc_x[nt], 0,0,0);
      acc_x[nt]  = __builtin_amdgcn_mfma_f32_16x16x32_bf16(ah, bl, acc_x[nt], 0,0,0);
      acc_hh[nt] = __builtin_amdgcn_mfma_f32_16x16x32_bf16(ah, bh, acc_hh[nt], 0,0,0);
    }
  }

  #pragma unroll
  for (int nt=0; nt<4; ++nt){
    int ocol = col0 + nt*16 + (lane & 15);
    if (ocol >= Nstore) continue;
    if (MODE == 4){
      int rbase = row0 + (lane>>4)*4;
      int xx = rbase >> 3, cb = rbase & 7;        // cb in {0,4}
      float4 vv;
      vv.x = acc_hh[nt][0] + acc_x[nt][0];
      vv.y = acc_hh[nt][1] + acc_x[nt][1];
      vv.z = acc_hh[nt][2] + acc_x[nt][2];
      vv.w = acc_hh[nt][3] + acc_x[nt][3];
      *(float4*)(out + ((((long)blockIdx.z*256 + xx)*256 + ocol)<<3) + cb) = vv;
      continue;
    }
    #pragma unroll
    for (int i=0; i<4; ++i){
      int orow = row0 + (lane>>4)*4 + i;
      float v = acc_hh[nt][i] + acc_x[nt][i];
      if (MODE == 1){
        float t = v + bias[ocol];
        out[(long)orow*Nstore + ocol] = 1.f/(1.f + expf(-t));
      } else if (MODE == 2){
        float t;
        if (ocol < 150) t = v + bias[ocol];
        else            t = (ocol == 150) ? 1.f : 0.f;
        u16 h,l; splitf(t,h,l);
        long idx = (long)orow*160 + ocol;
        ohi[idx] = h; olo[idx] = l;
      } else if (MODE == 3){
        int c = ocol/151, j = ocol - c*151;
        u16 h,l; splitf(v,h,l);
        long idx = ((long)orow*8 + c)*160 + j;
        ohi[idx] = h; olo[idx] = l;
      } else if (MODE == 5){
        float t = v + (ocol < 1200 ? bias[ocol] : bias2[ocol-1200]);
        long dst = (ocol < 1200)
                 ? ((long)orow*1200 + ocol)
                 : ((long)BT*1200 + (long)orow*1200 + (ocol-1200));
        out[dst] = t;
      }
    }
  }
}

// --------------------------- h-state init (hi-only fragment order) ----------
// h_ex: [2 dir][2 buf][HFRAG] u32. buf 1 <- h0 frag-order, buf 0 <- 0.
// u32 slot for (b,k): kt*256 + p*64 + sub*16 + b, value = hi(k)|hi(k+1)<<16,
// with kt=k>>5, k'=k&31, sub=k'>>3, p=(k'&7)>>1 (k even).
__global__ void k_init_hex(const float* __restrict__ h0, u32* __restrict__ h_ex){
  const int total = 2*2*HFRAG;
  for (int i = blockIdx.x*blockDim.x + threadIdx.x; i < total;
       i += gridDim.x*blockDim.x){
    int s = i % HFRAG;
    int buf = (i / HFRAG) & 1;
    int kt = s >> 8, r = s & 255, p = r >> 6, ln = r & 63, sub = ln >> 4;
    int k0 = kt*32 + sub*8 + p*2;
    u32 v = 0;
    if (buf == 1){
      u16 a = (k0   < H_) ? bf16_rne(h0[k0])   : (u16)0;
      u16 b = (k0+1 < H_) ? bf16_rne(h0[k0+1]) : (u16)0;
      v = ((u32)b << 16) | a;
    }
    h_ex[i] = v;
  }
}

// --------------------------- LSTM scan kernel -------------------------------
// grid = (NS, 2 dirs), 256 threads (4 waves, 1 wave/SIMD). R3 protocol:
// all-wave poll of NS per-WG flags, two barriers, tid0 flag after barrier 2.
__global__ __launch_bounds__(256, 1)
void k_lstm(const float* __restrict__ Zx,                // [2][BT][G3]
            const u16* __restrict__ Wrhi, const u16* __restrict__ Wrlo, // [2][G3][HP]
            const float* __restrict__ c0,
            u32* h_ex,                                   // [2][2][HFRAG]
            u32* flags,                                  // [T][2][NS]
            float* __restrict__ outf,                    // [BT][H2]
            u16* __restrict__ out_hi, u16* __restrict__ out_lo)
{
  const int s = blockIdx.x, dir = blockIdx.y;
  const int tid = threadIdx.x, lane = tid & 63, wave = tid >> 6;
  const int u0 = s*HS;
  const int kofs = (lane >> 4) * 8;
  const bf16x8 bz = {0,0,0,0,0,0,0,0};
  const f32x4 vz = {0.f,0.f,0.f,0.f};

  // ---- persistent W fragments (B operand), cols = slice's 60 gate columns --
  const int lc = wave*16 + (lane & 15);          // local col 0..63 (>=60 pad)
  const bool colok = lc < 3*HS;
  int gcol = 0;
  if (colok){ int gg = lc/HS, idx = lc - gg*HS; gcol = gg*400 + u0 + idx; }
  const u16* wph = Wrhi + ((long)dir*G3 + gcol)*HP;
  const u16* wpl = Wrlo + ((long)dir*G3 + gcol)*HP;
  bf16x8 bh[13], bl[13];
  #pragma unroll
  for (int kt=0; kt<13; ++kt){
    bh[kt] = colok ? *(const bf16x8*)(wph + kt*32 + kofs) : bz;
    bl[kt] = colok ? *(const bf16x8*)(wpl + kt*32 + kofs) : bz;
  }

  // ---- update mapping: tid<160: b = tid/10, units ku=u0+2*(tid%10), ku+1 ----
  const bool upd = (tid < 160);
  const int b_a = tid/10, up_a = tid - (tid/10)*10;
  const int ku  = u0 + 2*up_a;                   // even unit index (global k)
  float c_a0 = 0.f, c_a1 = 0.f;
  if (upd){ c_a0 = c0[ku]; c_a1 = c0[ku+1]; }

  const float* zxd = Zx + (long)dir*BT*G3;
  const long zbase = (long)b_a*T_*G3 + ku;

  u32* hex_d = h_ex + (long)dir*2*HFRAG;
  // producer u32 slot for (b_a, ku, ku+1):
  const int pkt = ku >> 5, pk = ku & 31;
  const int psub = pk >> 3, pp2 = (pk & 7) >> 1;
  const int pslot = pkt*256 + pp2*64 + (psub*16 + b_a);

  __shared__ float zlds[16][64];

  for (int q=0; q<T_; ++q){
    const int t = dir ? (T_-1-q) : q;

    // prefetch Zx (overlaps the poll)
    float2 zxi = {0.f,0.f}, zxj = {0.f,0.f}, zxo = {0.f,0.f};
    if (upd){
      const float* zp = zxd + zbase + (long)t*G3;
      zxi = *(const float2*)(zp);
      zxj = *(const float2*)(zp + 400);
      zxo = *(const float2*)(zp + 800);
    }

    // wait for all producers of h_{q-1}: all waves poll NS flags (R3)
    if (q > 0){
      const u32* f = flags + ((q-1)*2 + dir)*NS;
      while (true){
        int ok = (lane >= NS) ||
                 (__hip_atomic_load(f + lane, __ATOMIC_RELAXED,
                                    __HIP_MEMORY_SCOPE_AGENT) != 0u);
        if (__all(ok)) break;
        __builtin_amdgcn_s_sleep(1);
      }
    }

    // load h_{q-1}: 52 coalesced u32 agent loads (hi-only, bit_cast unpack)
    const u32* hx = hex_d + ((q&1)^1)*HFRAG;
    u32 w[13][4];
    #pragma unroll
    for (int kt=0; kt<13; ++kt){
      #pragma unroll
      for (int p=0; p<4; ++p)
        w[kt][p] = __hip_atomic_load(hx + kt*256 + p*64 + lane,
                                     __ATOMIC_RELAXED, __HIP_MEMORY_SCOPE_AGENT);
    }

    // z_slice = h_hi @ (W_hi + W_lo): 2 independent MFMA chains
    f32x4 a0 = vz, a1 = vz;
    #pragma unroll
    for (int kt=0; kt<13; ++kt){
      u32x4 av = {w[kt][0], w[kt][1], w[kt][2], w[kt][3]};
      bf16x8 ah = __builtin_bit_cast(bf16x8, av);
      a0 = __builtin_amdgcn_mfma_f32_16x16x32_bf16(ah, bh[kt], a0, 0,0,0);
      a1 = __builtin_amdgcn_mfma_f32_16x16x32_bf16(ah, bl[kt], a1, 0,0,0);
    }
    #pragma unroll
    for (int i=0; i<4; ++i)
      zlds[(lane>>4)*4 + i][lc] = a0[i] + a1[i];
    __syncthreads();                               // barrier 1: zlds ready

    // gate math + h publish (2 units per update thread)
    u32 hpk = 0; float hh0 = 0.f, hh1 = 0.f;
    u16 h0h=0,h0l=0,h1h=0,h1l=0;
    if (upd){
      const int uu = 2*up_a;
      float vi0 = zlds[b_a][uu]          + zxi.x;
      float vj0 = zlds[b_a][HS + uu]     + zxj.x;
      float vo0 = zlds[b_a][2*HS + uu]   + zxo.x;
      float vi1 = zlds[b_a][uu+1]        + zxi.y;
      float vj1 = zlds[b_a][HS + uu+1]   + zxj.y;
      float vo1 = zlds[b_a][2*HS + uu+1] + zxo.y;
      float ig0 = 1.f/(1.f + expf(-vi0));
      c_a0 = (1.f - ig0)*c_a0 + ig0*tanhf(vj0);
      hh0 = tanhf(c_a0) * (1.f/(1.f + expf(-vo0)));
      float ig1 = 1.f/(1.f + expf(-vi1));
      c_a1 = (1.f - ig1)*c_a1 + ig1*tanhf(vj1);
      hh1 = tanhf(c_a1) * (1.f/(1.f + expf(-vo1)));
      splitf(hh0,h0h,h0l); splitf(hh1,h1h,h1l);
      hpk = ((u32)h1h << 16) | h0h;
      __hip_atomic_store(hex_d + (q&1)*HFRAG + pslot, hpk,
                         __ATOMIC_RELAXED, __HIP_MEMORY_SCOPE_AGENT);
    }
    __syncthreads();   // barrier 2: drains each wave's vmcnt (h stores done)
    if (tid == 0)
      __hip_atomic_store(flags + (q*2 + dir)*NS + s, 1u, __ATOMIC_RELAXED,
                         __HIP_MEMORY_SCOPE_AGENT);
    // exports AFTER the flag: their drain overlaps next step's poll
    if (upd){
      long o = ((long)b_a*T_ + t)*H2 + dir*H_ + ku;
      float2 of = {hh0, hh1};
      *(float2*)(outf + o) = of;
      *(u32*)(out_hi + o) = (((u32)h1h)<<16) | h0h;
      *(u32*)(out_lo + o) = (((u32)h1l)<<16) | h0l;
    }
    (void)hpk;
  }
}

// --------------------------- highway combine --------------------------------
__global__ void k_highway(const float* __restrict__ G, const float* __restrict__ o1,
                          const float* __restrict__ o0,
                          u16* __restrict__ chi, u16* __restrict__ clo, long n){
  for (long i = (long)blockIdx.x*blockDim.x + threadIdx.x; i < n;
       i += (long)gridDim.x*blockDim.x){
    float g = G[i];
    float v = g*o1[i] + (1.f - g)*o0[i];
    u16 h,l; splitf(v,h,l);
    chi[i] = h; clo[i] = l;
  }
}

// ---------------------------------------------------------------------------
extern "C" void kernel_launch(void* const* d_in, const int* in_sizes, int n_in,
                              void* d_out, int out_size, void* d_ws, size_t ws_size,
                              hipStream_t stream)
{
  (void)in_sizes; (void)n_in; (void)out_size; (void)ws_size;
  const float* x    = (const float*)d_in[0];
  const float* W_f0 = (const float*)d_in[1];
  const float* b_f0 = (const float*)d_in[2];
  const float* W_b0 = (const float*)d_in[3];
  const float* b_b0 = (const float*)d_in[4];
  const float* W_f1 = (const float*)d_in[5];
  const float* b_f1 = (const float*)d_in[6];
  const float* W_b1 = (const float*)d_in[7];
  const float* b_b1 = (const float*)d_in[8];
  const float* h0   = (const float*)d_in[9];
  const float* c0   = (const float*)d_in[10];
  const float* W_hw = (const float*)d_in[11];
  const float* b_hw = (const float*)d_in[12];
  const float* W_s  = (const float*)d_in[13];
  const float* b_s  = (const float*)d_in[14];
  const float* W_e  = (const float*)d_in[15];
  const float* b_e  = (const float*)d_in[16];
  const float* U    = (const float*)d_in[17];

  char* ws = (char*)d_ws;
  size_t off = 0;
  auto A = [&](size_t bytes)->char*{
    char* p = ws + off; off = (off + bytes + 255) & ~(size_t)255; return p;
  };

  // ---- workspace layout ----
  u16* x_hi   = (u16*)A(BT*768L*2);          // reused later for s1/e1 family
  u16* x_lo   = (u16*)A(BT*768L*2);
  u16* Wx0_hi = (u16*)A(2400L*768*2);        // rows 0..1199 = f, 1200..2399 = b
  u16* Wx0_lo = (u16*)A(2400L*768*2);
  u16* Wr0_hi = (u16*)A(2L*1200*HP*2); u16* Wr0_lo=(u16*)A(2L*1200*HP*2);
  u16* Wx1_hi = (u16*)A(2400L*800*2);
  u16* Wx1_lo = (u16*)A(2400L*800*2);
  u16* Wr1_hi = (u16*)A(2L*1200*HP*2); u16* Wr1_lo=(u16*)A(2L*1200*HP*2);
  u16* Whw_hi = (u16*)A(800L*800*2);  u16* Whw_lo=(u16*)A(800L*800*2);
  u16* Ws_hi  = (u16*)A(150L*800*2);  u16* Ws_lo =(u16*)A(150L*800*2);
  u16* We_hi  = (u16*)A(150L*800*2);  u16* We_lo =(u16*)A(150L*800*2);
  u16* Ut_hi  = (u16*)A(1208L*160*2); u16* Ut_lo =(u16*)A(1208L*160*2);
  float* Zx   = (float*)A(2L*BT*G3*4);       // 39.3 MB (reused for tmp hi/lo)
  u32* h_ex   = (u32*)A(2L*2*HFRAG*4);
  u32* flags  = (u32*)A(2L*T_*2*NS*4);       // [layer][T][dir][NS]
  float* out0f= (float*)A((long)BT*H2*4);
  u16* out0_hi= (u16*)A((long)BT*H2*2); u16* out0_lo=(u16*)A((long)BT*H2*2);
  float* out1f= (float*)A((long)BT*H2*4);
  u16* out1_hi= (u16*)A((long)BT*H2*2); u16* out1_lo=(u16*)A((long)BT*H2*2);
  float* Gbuf = (float*)A((long)BT*H2*4);
  u16* cur_hi = (u16*)A((long)BT*H2*2); u16* cur_lo=(u16*)A((long)BT*H2*2);

  // overlays
  char* xreg = (char*)x_hi;                  // x dead after layer-0 proj GEMM
  u16*   s1_hi = (u16*)xreg;
  u16*   s1_lo = (u16*)(xreg + 1310720);
  u16*   e1_hi = (u16*)(xreg + 2*1310720);
  u16*   e1_lo = (u16*)(xreg + 3*1310720);
  u16* tmp_hi = (u16*)Zx;                    // Zx dead after layer-1 LSTM
  u16* tmp_lo = tmp_hi + 32768L*160;
  float* outp = (float*)d_out;

  // ---- transpose/convert jobs ----
  TJobs tj;
  auto setj=[&](int k,const float* in,int ld,int r0,int R,int Rp,int Cc,u16* oh,u16* ol){
    tj.j[k].in=in; tj.j[k].ld=ld; tj.j[k].r0=r0; tj.j[k].R=R; tj.j[k].Rpad=Rp;
    tj.j[k].Cc=Cc; tj.j[k].ohi=oh; tj.j[k].olo=ol;
  };
  const long WRD = 1200L*HP;
  setj(0,  W_f0,1200,  0,768,768,1200, Wx0_hi, Wx0_lo);
  setj(1,  W_b0,1200,  0,768,768,1200, Wx0_hi+1200L*768, Wx0_lo+1200L*768);
  setj(2,  W_f0,1200,768,400,HP ,1200, Wr0_hi, Wr0_lo);
  setj(3,  W_b0,1200,768,400,HP ,1200, Wr0_hi+WRD, Wr0_lo+WRD);
  setj(4,  W_f1,1200,  0,800,800,1200, Wx1_hi, Wx1_lo);
  setj(5,  W_b1,1200,  0,800,800,1200, Wx1_hi+1200L*800, Wx1_lo+1200L*800);
  setj(6,  W_f1,1200,800,400,HP ,1200, Wr1_hi, Wr1_lo);
  setj(7,  W_b1,1200,800,400,HP ,1200, Wr1_hi+WRD, Wr1_lo+WRD);
  setj(8,  W_hw, 800,  0,800,800, 800, Whw_hi,Whw_lo);
  setj(9,  W_s,  150,  0,800,800, 150, Ws_hi, Ws_lo);
  setj(10, W_e,  150,  0,800,800, 150, We_hi, We_lo);
  setj(11, U,   1208,  0,151,160,1208, Ut_hi, Ut_lo);

  // ---- pipeline ----
  hipMemsetAsync(flags, 0, 2L*T_*2*NS*4, stream);
  k_cvt<<<4096,256,0,stream>>>(x, x_hi, x_lo, (long)BT*768, 1,1,1);
  k_tcvt<<<dim3(512,12),256,0,stream>>>(tj);
  k_init_hex<<<52,256,0,stream>>>(h0, h_ex);

  // layer 0: merged f+b input projection (one dispatch, A read once)
  k_gemm<5><<<dim3(38,64),256,0,stream>>>(x_hi,x_lo,768, Wx0_hi,Wx0_lo,
                                          b_f0, b_b0, Zx, nullptr,nullptr, 2400,2400);
  k_lstm<<<dim3(NS,2),256,0,stream>>>(Zx, Wr0_hi,Wr0_lo, c0, h_ex, flags,
                                      out0f, out0_hi, out0_lo);
  // layer 1: merged projection (input = concat(xf,xb) of layer 0)
  k_gemm<5><<<dim3(38,64),256,0,stream>>>(out0_hi,out0_lo,800, Wx1_hi,Wx1_lo,
                                          b_f1, b_b1, Zx, nullptr,nullptr, 2400,2400);
  k_init_hex<<<52,256,0,stream>>>(h0, h_ex);
  k_lstm<<<dim3(NS,2),256,0,stream>>>(Zx, Wr1_hi,Wr1_lo, c0, h_ex,
                                      flags + (long)T_*2*NS,
                                      out1f, out1_hi, out1_lo);
  // highway: gate = sigmoid(out1 @ W_hw + b_hw); cur = g*out1 + (1-g)*out0
  k_gemm<1><<<dim3(13,64),256,0,stream>>>(out1_hi,out1_lo,800, Whw_hi,Whw_lo,
                                          b_hw, nullptr, Gbuf, nullptr,nullptr, 800,800);
  k_highway<<<4096,256,0,stream>>>(Gbuf, out1f, out0f, cur_hi, cur_lo, (long)BT*H2);
  // start/end projections -> s1/e1 bf16 hi/lo with appended 1.0 col, K-pad 160
  k_gemm<2><<<dim3(3,64),256,0,stream>>>(cur_hi,cur_lo,800, Ws_hi,Ws_lo,
                                         b_s, nullptr, nullptr, s1_hi,s1_lo, 150,160);
  k_gemm<2><<<dim3(3,64),256,0,stream>>>(cur_hi,cur_lo,800, We_hi,We_lo,
                                         b_e, nullptr, nullptr, e1_hi,e1_lo, 150,160);
  // biaffine stage 1: tmp[b,x,c,j] = sum_i s1[b,x,i] U[i,c,j]  (bf16 hi/lo out)
  hipMemsetAsync(tmp_hi, 0, 32768L*160*2*2, stream);   // zero incl. j=151..159 pad
  k_gemm<3><<<dim3(19,64),256,0,stream>>>(s1_hi,s1_lo,160, Ut_hi,Ut_lo,
                                          nullptr, nullptr, nullptr, tmp_hi,tmp_lo, 1208,1208);
  // biaffine stage 2: out[b,x,y,c] = sum_j tmp[b,x,c,j] e1[b,y,j]
  k_gemm<4><<<dim3(4,32,16),256,0,stream>>>(tmp_hi,tmp_lo,160, e1_hi,e1_lo,
                                            nullptr, nullptr, outp, nullptr,nullptr, 256,256);
}